// Round 7
// baseline (177.109 us; speedup 1.0000x reference)
//
#include <hip/hip_runtime.h>
#include <stdint.h>

// Problem constants (from reference)
#define N_NODES 50000
#define DEG     32
#define IN_DIM  256
#define K1      512   // 2*IN_DIM
#define HID     256
#define OUT_DIM 128

// fp8 gather tiling
#define NCHUNK  4
#define CDIM    64                          // dims per chunk (64 B fp8 per node-chunk)
#define SLICE8  ((size_t)N_NODES * CDIM)    // bytes per chunk slice (3.2 MB)
#define GT      16                          // nodes per gather block

// GEMM tiling (classic LDS-streamed W, 2 blocks/CU)
#define MT2    64                           // nodes per block
#define NT2B   ((N_NODES + MT2 - 1) / MT2)  // 782 blocks
#define KC     64                           // k per chunk step
#define HSTR2  264                          // sH row stride (u16), padded

typedef __bf16 bf16x8 __attribute__((ext_vector_type(8)));
typedef float  f32x4  __attribute__((ext_vector_type(4)));
typedef float  f32x2  __attribute__((ext_vector_type(2)));

__device__ __forceinline__ unsigned short f2bf(float f) {
    union { float f; unsigned u; } v; v.f = f;
    unsigned r = v.u + 0x7fffu + ((v.u >> 16) & 1u);  // RNE (inputs finite)
    return (unsigned short)(r >> 16);
}
__device__ __forceinline__ int clampN(int v) {
    return v < 0 ? 0 : (v >= N_NODES ? N_NODES - 1 : v);
}
__device__ __forceinline__ void async_copy16(const void* g, void* l) {
    __builtin_amdgcn_global_load_lds(
        (const __attribute__((address_space(1))) void*)g,
        (__attribute__((address_space(3))) void*)l, 16, 0, 0);
}

// ---------------- merged prep: feat->bf16 + fp8 tiled; W1/W2->bf16; nbr->u16 ----------------
#define FEAT_BLKS ((N_NODES + 7) / 8)   // 6250
__global__ __launch_bounds__(256)
void prep_all(const float* __restrict__ feat,
              const float* __restrict__ W1, const float* __restrict__ W2,
              const int*   __restrict__ nbr,
              unsigned short* __restrict__ featb,   // [N,256] bf16
              unsigned char*  __restrict__ featF8,  // [4][N][64] fp8 e4m3
              unsigned short* __restrict__ W1b, unsigned short* __restrict__ W2b,
              unsigned short* __restrict__ nbr16)
{
    const int t = threadIdx.x;
    if (blockIdx.x < FEAT_BLKS) {
        const int node = blockIdx.x * 8 + (t >> 5);  // 8 nodes/block
        const int seg  = t & 31;                     // dims seg*8 .. seg*8+7
        if (node < N_NODES) {
            const float4* src = (const float4*)(feat + (size_t)node * IN_DIM + seg * 8);
            float4 f0 = src[0], f1 = src[1];
            ushort4 o0, o1;
            o0.x = f2bf(f0.x); o0.y = f2bf(f0.y); o0.z = f2bf(f0.z); o0.w = f2bf(f0.w);
            o1.x = f2bf(f1.x); o1.y = f2bf(f1.y); o1.z = f2bf(f1.z); o1.w = f2bf(f1.w);
            unsigned short* db = featb + (size_t)node * IN_DIM + seg * 8;
            *(ushort4*)db       = o0;
            *(ushort4*)(db + 4) = o1;
            int u0 = 0, u1 = 0;
            u0 = __builtin_amdgcn_cvt_pk_fp8_f32(f0.x, f0.y, u0, false);
            u0 = __builtin_amdgcn_cvt_pk_fp8_f32(f0.z, f0.w, u0, true);
            u1 = __builtin_amdgcn_cvt_pk_fp8_f32(f1.x, f1.y, u1, false);
            u1 = __builtin_amdgcn_cvt_pk_fp8_f32(f1.z, f1.w, u1, true);
            const int c   = seg >> 3;
            const int off = (seg & 7) * 8;
            unsigned char* d8 = featF8 + (size_t)c * SLICE8 + (size_t)node * CDIM + off;
            ((int*)d8)[0] = u0;
            ((int*)d8)[1] = u1;
        }
    } else {
        const int bid = blockIdx.x - FEAT_BLKS;           // 0..255
        const int stride = 256 * 256 * 4;
        const int tid4 = (bid * 256 + t) * 4;
        for (int i = tid4; i < HID * K1; i += stride) {
            float4 f = *(const float4*)(W1 + i);
            ushort4 o; o.x = f2bf(f.x); o.y = f2bf(f.y); o.z = f2bf(f.z); o.w = f2bf(f.w);
            *(ushort4*)(W1b + i) = o;
        }
        for (int i = tid4; i < OUT_DIM * HID; i += stride) {
            float4 f = *(const float4*)(W2 + i);
            ushort4 o; o.x = f2bf(f.x); o.y = f2bf(f.y); o.z = f2bf(f.z); o.w = f2bf(f.w);
            *(ushort4*)(W2b + i) = o;
        }
        for (int i = tid4; i < N_NODES * DEG; i += stride) {
            int4 v = *(const int4*)(nbr + i);
            ushort4 o;
            o.x = (unsigned short)clampN(v.x); o.y = (unsigned short)clampN(v.y);
            o.z = (unsigned short)clampN(v.z); o.w = (unsigned short)clampN(v.w);
            *(ushort4*)(nbr16 + i) = o;
        }
    }
}

// ---------------- gather + mean: fp8 slices, round-0 proven shape ----------------
// thread = (node-slot grp 0..15, dword ln 0..15); 4 B/lane; all 32 loads issued
// before any convert (max MLP, single vmcnt drain). ~0.27 lines/cy/CU measured
// cap (random-line throughput) — fastest of 3 shapes tried (39/44/47 µs).
__global__ __launch_bounds__(256)
void gather_mean_fp8(const unsigned char*  __restrict__ featF8,
                     const unsigned short* __restrict__ nbr16,
                     unsigned short*       __restrict__ meanb)  // [N,256] bf16
{
    __shared__ unsigned short sIdx[GT * DEG];  // 1 KB
    const int tid  = threadIdx.x;
    const int c    = blockIdx.y;
    const int base = blockIdx.x * GT;          // N % GT == 0: no tail

    if (tid < 128) {
        *(ushort4*)(sIdx + tid * 4) =
            *(const ushort4*)(nbr16 + (size_t)base * DEG + tid * 4);
    }
    __syncthreads();

    const unsigned char* slice = featF8 + (size_t)c * SLICE8;
    const int grp = tid >> 4;     // node slot 0..15
    const int ln  = tid & 15;     // dims 4*ln .. 4*ln+3 of the chunk
    const unsigned short* idxr = sIdx + grp * DEG;

    // all 32 loads issued before any use: max memory-level parallelism
    unsigned vv[DEG];
    #pragma unroll
    for (int j = 0; j < DEG; ++j) {
        int nb = idxr[j];
        vv[j] = *(const unsigned*)(slice + (size_t)nb * CDIM + ln * 4);
    }
    float s0 = 0.f, s1 = 0.f, s2 = 0.f, s3 = 0.f;
    #pragma unroll
    for (int j = 0; j < DEG; ++j) {
        f32x2 lo = __builtin_amdgcn_cvt_pk_f32_fp8(vv[j], false);
        f32x2 hi = __builtin_amdgcn_cvt_pk_f32_fp8(vv[j], true);
        s0 += lo[0]; s1 += lo[1]; s2 += hi[0]; s3 += hi[1];
    }
    const float sc = 1.0f / 32.0f;
    ushort4 o;
    o.x = f2bf(s0 * sc); o.y = f2bf(s1 * sc);
    o.z = f2bf(s2 * sc); o.w = f2bf(s3 * sc);
    const int node = base + grp;
    *(ushort4*)(meanb + (size_t)node * IN_DIM + c * CDIM + ln * 4) = o;
}

// ---------------- classic LDS-streamed fused 2-layer GEMM (2 blocks/CU) ----------------
// Rounds 0-6 post-mortem: every W-in-registers persistent variant sat at 41-50us
// (MfmaUtil 12-14%, 1 block/CU, 2 waves/SIMD, serial stage->drain->compute chain —
// exposed latency, not spills). Fix: textbook §5 structure. 782 one-shot blocks,
// 64 nodes each, W1 streamed through LDS in [256n x 64k] chunks (8 steps), W2 in
// [128n x 64k] chunks (4 steps). Live VGPRs ~90 -> honest (512,2) = 2 blocks/CU;
// the other block's MFMA hides every stage drain.
// LDS rows are 128 B -> XOR-swizzle granules via pre-swizzled GLOBAL source
// (m173: global_load_lds dest must stay linear): slot s of row i holds source
// granule s^(i&7); reads use slot (4*kk+q)^(r&7) (row%8 == r%8 for all fragments).
// K-accumulation order (k = 0,32,...,480 ascending) identical to prior rounds ->
// bit-identical output.
// MFMA fragment layouts (measured, learn_hip m89/m91/m120):
//   A operand: lane holds A[m = lane&15][k = (lane>>4)*8 + j], j=0..7
//   B operand (W row-major [n][k]): lane holds W[n = lane&15][k = (lane>>4)*8 + j]
//   C/D: col(n) = lane&15, row(m) = (lane>>4)*4 + reg
__global__ __launch_bounds__(512, 2)
void sage_gemm2(const unsigned short* __restrict__ featb,  // [N,256] bf16
                const unsigned short* __restrict__ meanb,  // [N,256] bf16
                const unsigned short* __restrict__ W1b,    // [256,512] bf16
                const float*          __restrict__ b1,
                const unsigned short* __restrict__ W2b,    // [128,256] bf16
                const float*          __restrict__ b2,
                float*                __restrict__ out)    // [N,128]
{
    __shared__ __align__(16) unsigned short sA[MT2 * KC];     //  8192 B  [64 m][64 k] swizzled
    __shared__ __align__(16) unsigned short sW[256 * KC];     // 32768 B  [256 n][64 k] swizzled
    __shared__ __align__(16) unsigned short sH[MT2 * HSTR2];  // 33792 B  (74752 total -> 2 blk/CU)

    const int tid  = threadIdx.x;
    const int lane = tid & 63;
    const int wave = tid >> 6;     // 0..7
    const int r    = lane & 15;
    const int q    = lane >> 4;
    const int mh   = wave >> 2;    // m-half: rows mh*32 + 0..31
    const int nq   = wave & 3;     // phase-A n-quarter: cols nq*64 + 0..63

    const int tbase = blockIdx.x * MT2;

    // ---- Phase A: h = relu([self|mean] @ W1^T + b1), K=512 in 8 chunks of 64 ----
    f32x4 acc1[2][4];
    #pragma unroll
    for (int mt = 0; mt < 2; ++mt)
        #pragma unroll
        for (int nt = 0; nt < 4; ++nt)
            acc1[mt][nt] = (f32x4){0.f, 0.f, 0.f, 0.f};

    for (int kc = 0; kc < 8; ++kc) {
        __syncthreads();   // previous chunk's reads of sA/sW complete
        // stage A chunk: 1 async/wave; row i = wave*8 + (lane>>3), 8 granules of 16 B
        {
            const int i = wave * 8 + (lane >> 3);
            const int node = clampN(tbase + i);
            const int g = (lane & 7) ^ (i & 7);                    // pre-swizzled source granule
            const unsigned short* src = (kc < 4 ? featb : meanb)
                + (size_t)node * IN_DIM + (kc & 3) * KC + g * 8;
            async_copy16(src, &sA[wave * 8 * KC]);
        }
        // stage W1 chunk: 4 asyncs/wave; rows n = wave*32 + j*8 + (lane>>3)
        #pragma unroll
        for (int j = 0; j < 4; ++j) {
            const int n = wave * 32 + j * 8 + (lane >> 3);
            const int g = (lane & 7) ^ (n & 7);
            async_copy16(W1b + (size_t)n * K1 + kc * KC + g * 8,
                         &sW[(wave * 32 + j * 8) * KC]);
        }
        __syncthreads();   // compiler drains vmcnt before s_barrier: chunks ready

        #pragma unroll
        for (int kk = 0; kk < 2; ++kk) {
            bf16x8 a[2], w[4];
            #pragma unroll
            for (int mt = 0; mt < 2; ++mt)
                a[mt] = *(const bf16x8*)(&sA[(mh * 32 + mt * 16 + r) * KC
                                             + ((kk * 4 + q) ^ (r & 7)) * 8]);
            #pragma unroll
            for (int nt = 0; nt < 4; ++nt)
                w[nt] = *(const bf16x8*)(&sW[(nq * 64 + nt * 16 + r) * KC
                                             + ((kk * 4 + q) ^ (r & 7)) * 8]);
            #pragma unroll
            for (int mt = 0; mt < 2; ++mt)
                #pragma unroll
                for (int nt = 0; nt < 4; ++nt)
                    acc1[mt][nt] = __builtin_amdgcn_mfma_f32_16x16x32_bf16(
                        a[mt], w[nt], acc1[mt][nt], 0, 0, 0);
        }
    }

    // bias + relu -> sH (padded stride, no swizzle needed)
    #pragma unroll
    for (int nt = 0; nt < 4; ++nt) {
        const int n = nq * 64 + nt * 16 + r;
        const float bias = b1[n];
        #pragma unroll
        for (int mt = 0; mt < 2; ++mt)
            #pragma unroll
            for (int g = 0; g < 4; ++g) {
                const int m = mh * 32 + mt * 16 + q * 4 + g;
                float v = acc1[mt][nt][g] + bias;
                sH[m * HSTR2 + n] = f2bf(v > 0.f ? v : 0.f);
            }
    }

    // ---- Phase B: out = relu(h @ W2^T + b2), K=256 in 4 chunks of 64 ----
    const int nh = wave & 3;       // n-group: cols nh*32 + 0..31
    f32x4 acc2[2][2];
    #pragma unroll
    for (int mt = 0; mt < 2; ++mt)
        #pragma unroll
        for (int nt = 0; nt < 2; ++nt)
            acc2[mt][nt] = (f32x4){0.f, 0.f, 0.f, 0.f};

    for (int kc = 0; kc < 4; ++kc) {
        __syncthreads();   // kc=0: sH writes + phase-A sW reads complete; else prev reads done
        // stage W2 chunk: 2 asyncs/wave; rows n = wave*16 + j*8 + (lane>>3)  (0..127)
        #pragma unroll
        for (int j = 0; j < 2; ++j) {
            const int n = wave * 16 + j * 8 + (lane >> 3);
            const int g = (lane & 7) ^ (n & 7);
            async_copy16(W2b + (size_t)n * HID + kc * KC + g * 8,
                         &sW[(wave * 16 + j * 8) * KC]);
        }
        __syncthreads();

        #pragma unroll
        for (int kk = 0; kk < 2; ++kk) {
            bf16x8 h[2], w[2];
            #pragma unroll
            for (int mt = 0; mt < 2; ++mt)
                h[mt] = *(const bf16x8*)(&sH[(mh * 32 + mt * 16 + r) * HSTR2
                                             + kc * KC + kk * 32 + q * 8]);
            #pragma unroll
            for (int nt = 0; nt < 2; ++nt)
                w[nt] = *(const bf16x8*)(&sW[(nh * 32 + nt * 16 + r) * KC
                                             + ((kk * 4 + q) ^ (r & 7)) * 8]);
            #pragma unroll
            for (int mt = 0; mt < 2; ++mt)
                #pragma unroll
                for (int nt = 0; nt < 2; ++nt)
                    acc2[mt][nt] = __builtin_amdgcn_mfma_f32_16x16x32_bf16(
                        h[mt], w[nt], acc2[mt][nt], 0, 0, 0);
        }
    }

    // bias + relu -> out
    #pragma unroll
    for (int nt = 0; nt < 2; ++nt) {
        const int o = nh * 32 + nt * 16 + r;
        const float bias = b2[o];
        #pragma unroll
        for (int mt = 0; mt < 2; ++mt)
            #pragma unroll
            for (int g = 0; g < 4; ++g) {
                const int m = mh * 32 + mt * 16 + q * 4 + g;
                const int node = tbase + m;
                if (node < N_NODES) {
                    float v = acc2[mt][nt][g] + bias;
                    out[(size_t)node * OUT_DIM + o] = v > 0.f ? v : 0.f;
                }
            }
    }
}

// ---------------- naive fp32 fallback (only if ws too small) ----------------
__global__ __launch_bounds__(256)
void sage_naive(const float* __restrict__ feat, const int* __restrict__ nbr,
                const float* __restrict__ W1, const float* __restrict__ b1,
                const float* __restrict__ W2, const float* __restrict__ b2,
                float* __restrict__ out) {
    __shared__ float comb[K1];
    __shared__ float h[HID];
    const int node = blockIdx.x;
    const int t = threadIdx.x;  // 256
    comb[t] = feat[(size_t)node * IN_DIM + t];
    float acc = 0.f;
    for (int d = 0; d < DEG; ++d) {
        int nb = clampN(nbr[node * DEG + d]);
        acc += feat[(size_t)nb * IN_DIM + t];
    }
    comb[IN_DIM + t] = acc * (1.0f / 32.0f);
    __syncthreads();
    float s = b1[t];
    for (int k = 0; k < K1; ++k) s += comb[k] * W1[(size_t)t * K1 + k];
    h[t] = s > 0.f ? s : 0.f;
    __syncthreads();
    if (t < OUT_DIM) {
        float s2 = b2[t];
        for (int k = 0; k < HID; ++k) s2 += h[k] * W2[(size_t)t * HID + k];
        out[(size_t)node * OUT_DIM + t] = s2 > 0.f ? s2 : 0.f;
    }
}

extern "C" void kernel_launch(void* const* d_in, const int* in_sizes, int n_in,
                              void* d_out, int out_size, void* d_ws, size_t ws_size,
                              hipStream_t stream) {
    const float* feat = (const float*)d_in[0];
    const int*   nbr  = (const int*)d_in[1];
    const float* W1   = (const float*)d_in[2];
    const float* b1   = (const float*)d_in[3];
    const float* W2   = (const float*)d_in[4];
    const float* b2   = (const float*)d_in[5];
    float* out = (float*)d_out;

    const size_t feat_elems = (size_t)N_NODES * IN_DIM;   // 12.8M
    const size_t w1_elems   = (size_t)HID * K1;
    const size_t w2_elems   = (size_t)OUT_DIM * HID;
    const size_t mean_elems = (size_t)N_NODES * IN_DIM;
    const size_t idx_elems  = (size_t)N_NODES * DEG;
    const size_t u16_elems  = feat_elems + w1_elems + w2_elems + mean_elems + idx_elems;
    const size_t need = u16_elems * sizeof(unsigned short)
                      + (size_t)NCHUNK * SLICE8;          // ~67.6 MB

    if (ws_size >= need) {
        unsigned short* featb  = (unsigned short*)d_ws;
        unsigned short* W1b    = featb + feat_elems;
        unsigned short* W2b    = W1b + w1_elems;
        unsigned short* meanb  = W2b + w2_elems;
        unsigned short* nbr16  = meanb + mean_elems;
        unsigned char*  featF8 = (unsigned char*)(nbr16 + idx_elems);

        prep_all<<<FEAT_BLKS + 256, 256, 0, stream>>>(feat, W1, W2, nbr,
                                                      featb, featF8, W1b, W2b, nbr16);
        gather_mean_fp8<<<dim3(N_NODES / GT, NCHUNK), 256, 0, stream>>>(featF8, nbr16, meanb);
        sage_gemm2<<<NT2B, 512, 0, stream>>>(featb, meanb, W1b, b1, W2b, b2, out);
    } else {
        sage_naive<<<N_NODES, 256, 0, stream>>>(feat, nbr, W1, b1, W2, b2, out);
    }
}